// Round 1
// baseline (1330.161 us; speedup 1.0000x reference)
//
#include <hip/hip_runtime.h>
#include <math.h>

#define NROWS 262144
#define NC    1000
#define NCELL (NC * NC)
#define SCALEF 1.0f

// ---- workspace layout (bytes) ----
// [0, 4e6)        float cm[NC*NC]      counts (+cost_matrix input)
// [4e6, 8e6)      float S[NC*NC]       sum of glp per (t,p) cell
// [8e6, +8)       double losssum
// [8e6+8, +4)     unsigned maxbits
// [8e6+12, +4)    unsigned done counter
#define WS_S_OFF    4000000
#define WS_SCAL_OFF 8000000

__global__ __launch_bounds__(256) void k_init(const float* __restrict__ cost_in,
                                              float* __restrict__ cm,
                                              float* __restrict__ S,
                                              double* __restrict__ losssum,
                                              unsigned* __restrict__ scal) {
    int i = blockIdx.x * 256 + threadIdx.x;
    if (i < NCELL) { cm[i] = cost_in[i]; S[i] = 0.f; }
    if (i == 0) { *losssum = 0.0; scal[0] = 0u; scal[1] = 0u; }
}

// One wave (64 lanes) per TWO rows; each lane holds 16 elements per row (4x float4).
// Element e of a row: segment q = e>>8, lane = (e&255)>>2, sub = e&3.
// Two rows per wave: 8 independent dwordx4 loads in flight (2x MLP), two
// independent shuffle-reduction chains interleaved, atomic tail amortized.
__global__ __launch_bounds__(256) void k_row(const float* __restrict__ outs,
                                             const int* __restrict__ targets,
                                             float* __restrict__ cm,
                                             float* __restrict__ S) {
    int wid  = blockIdx.x * 4 + (threadIdx.x >> 6);
    int lane = threadIdx.x & 63;
    int row0 = wid * 2;

    const float* rp0 = outs + (size_t)row0 * NC;
    const float* rp1 = rp0 + NC;

    int t0 = targets[row0];
    int t1 = targets[row0 + 1];

    bool has3 = (4 * lane) < (NC - 768);   // 4*lane < 232

    float4 a0 = *(const float4*)(rp0 + 4 * lane);
    float4 a1 = *(const float4*)(rp0 + 256 + 4 * lane);
    float4 a2 = *(const float4*)(rp0 + 512 + 4 * lane);
    float4 b0 = *(const float4*)(rp1 + 4 * lane);
    float4 b1 = *(const float4*)(rp1 + 256 + 4 * lane);
    float4 b2 = *(const float4*)(rp1 + 512 + 4 * lane);
    float4 a3, b3;
    if (has3) {
        a3 = *(const float4*)(rp0 + 768 + 4 * lane);
        b3 = *(const float4*)(rp1 + 768 + 4 * lane);
    } else {
        a3 = make_float4(-INFINITY, -INFINITY, -INFINITY, -INFINITY);
        b3 = a3;
    }

    float tv0 = rp0[t0];                   // after vector loads: L1 hit
    float tv1 = rp1[t1];

    float va[16] = {a0.x, a0.y, a0.z, a0.w,
                    a1.x, a1.y, a1.z, a1.w,
                    a2.x, a2.y, a2.z, a2.w,
                    a3.x, a3.y, a3.z, a3.w};
    float vb[16] = {b0.x, b0.y, b0.z, b0.w,
                    b1.x, b1.y, b1.z, b1.w,
                    b2.x, b2.y, b2.z, b2.w,
                    b3.x, b3.y, b3.z, b3.w};

    // per-lane max + argmax (first occurrence wins ties), both rows interleaved
    float mxa = -INFINITY, mxb = -INFINITY;
    int   ia = 0x7fffffff, ib = 0x7fffffff;
    #pragma unroll
    for (int q = 0; q < 16; ++q) {
        int idx = 256 * (q >> 2) + 4 * lane + (q & 3);
        float x0 = va[q];
        float x1 = vb[q];
        if (x0 > mxa || (x0 == mxa && idx < ia)) { mxa = x0; ia = idx; }
        if (x1 > mxb || (x1 == mxb && idx < ib)) { mxb = x1; ib = idx; }
    }
    #pragma unroll
    for (int off = 32; off; off >>= 1) {
        float oma = __shfl_xor(mxa, off, 64);
        int   oia = __shfl_xor(ia,  off, 64);
        float omb = __shfl_xor(mxb, off, 64);
        int   oib = __shfl_xor(ib,  off, 64);
        if (oma > mxa || (oma == mxa && oia < ia)) { mxa = oma; ia = oia; }
        if (omb > mxb || (omb == mxb && oib < ib)) { mxb = omb; ib = oib; }
    }

    // sum of exp(x - mx); -inf pad entries contribute 0
    float sa = 0.f, sb = 0.f;
    #pragma unroll
    for (int q = 0; q < 16; ++q) {
        sa += __expf(va[q] - mxa);
        sb += __expf(vb[q] - mxb);
    }
    #pragma unroll
    for (int off = 32; off; off >>= 1) {
        sa += __shfl_xor(sa, off, 64);
        sb += __shfl_xor(sb, off, 64);
    }

    if (lane == 0) {
        float lp0 = tv0 - mxa - __logf(sa);   // log_softmax at target, row0
        float lp1 = tv1 - mxb - __logf(sb);   // row1
        int c0 = t0 * NC + ia;
        int c1 = t1 * NC + ib;
        atomicAdd(&cm[c0], 1.0f);             // confusion counts
        atomicAdd(&cm[c1], 1.0f);
        atomicAdd(&S[c0], lp0);               // glp sums per (t,p)
        atomicAdd(&S[c1], lp1);
    }
}

__global__ __launch_bounds__(256) void k_cmmax(const float* __restrict__ cm,
                                               unsigned* __restrict__ maxbits) {
    __shared__ float red[4];
    float val = 0.f;
    for (int idx = blockIdx.x * 256 + threadIdx.x; idx < NCELL; idx += gridDim.x * 256) {
        int r = idx / NC;
        int c = idx - r * NC;
        float x = (r == c) ? 0.f : cm[idx];   // zero diagonal on the fly
        val = fmaxf(val, x);
    }
    #pragma unroll
    for (int off = 32; off; off >>= 1) val = fmaxf(val, __shfl_xor(val, off, 64));
    if ((threadIdx.x & 63) == 0) red[threadIdx.x >> 6] = val;
    __syncthreads();
    if (threadIdx.x == 0) {
        val = fmaxf(fmaxf(red[0], red[1]), fmaxf(red[2], red[3]));
        atomicMax(maxbits, __float_as_uint(val));   // counts >= 0, uint-order ok
    }
}

// loss_sum = sum over cells of S[i] * (1 + [r!=c] * cm[i]/mx); last block finalizes.
__global__ __launch_bounds__(256) void k_loss(const float* __restrict__ cm,
                                              const float* __restrict__ S,
                                              const unsigned* __restrict__ maxbits,
                                              double* __restrict__ losssum,
                                              unsigned* __restrict__ counter,
                                              float* __restrict__ out) {
    __shared__ double red[4];
    float inv_mx = SCALEF / __uint_as_float(*maxbits);
    double part = 0.0;
    for (int idx = blockIdx.x * 256 + threadIdx.x; idx < NCELL; idx += gridDim.x * 256) {
        int r = idx / NC;
        int c = idx - r * NC;
        float sv = S[idx];
        float cost = (r == c) ? 1.0f : fmaf(cm[idx], inv_mx, 1.0f);
        part += (double)(sv * cost);
    }
    #pragma unroll
    for (int off = 32; off; off >>= 1) part += __shfl_xor(part, off, 64);
    if ((threadIdx.x & 63) == 0) red[threadIdx.x >> 6] = part;
    __syncthreads();
    if (threadIdx.x == 0) {
        part = red[0] + red[1] + red[2] + red[3];
        atomicAdd(losssum, part);
        __threadfence();
        unsigned prev = atomicAdd(counter, 1u);
        if (prev == gridDim.x - 1) {
            double total = atomicAdd(losssum, 0.0);  // coherent read-back
            out[0] = (float)(-total / (double)NROWS);
        }
    }
}

extern "C" void kernel_launch(void* const* d_in, const int* in_sizes, int n_in,
                              void* d_out, int out_size, void* d_ws, size_t ws_size,
                              hipStream_t stream) {
    const float* outs    = (const float*)d_in[0];
    const float* cost_in = (const float*)d_in[1];
    const int*   targets = (const int*)d_in[2];

    char* ws = (char*)d_ws;
    float*    cm      = (float*)ws;
    float*    S       = (float*)(ws + WS_S_OFF);
    double*   losssum = (double*)(ws + WS_SCAL_OFF);
    unsigned* maxbits = (unsigned*)(ws + WS_SCAL_OFF + 8);
    unsigned* counter = (unsigned*)(ws + WS_SCAL_OFF + 12);

    k_init<<<(NCELL + 255) / 256, 256, 0, stream>>>(cost_in, cm, S, losssum, maxbits);
    k_row<<<NROWS / 8, 256, 0, stream>>>(outs, targets, cm, S);
    k_cmmax<<<512, 256, 0, stream>>>(cm, maxbits);
    k_loss<<<512, 256, 0, stream>>>(cm, S, maxbits, losssum, counter, (float*)d_out);
}